// Round 13
// baseline (334.768 us; speedup 1.0000x reference)
//
#include <hip/hip_runtime.h>

#define N_USERS 100000
#define N_ITEMS 50000
#define N_NODES 150000   // N_USERS + N_ITEMS
#define DIM 64
#define NQ 4096
#define GROUP 256
#define GSH 8
#define NG ((N_NODES + GROUP - 1) / GROUP)   // 586 groups of 256 nodes
#define NBLK_A 512
#define NT (NG * NBLK_A)                      // 300032 count-table entries
#define NSB2 ((NT + 1023) / 1024)             // 293 scan chunks

typedef __attribute__((ext_vector_type(4))) _Float16 h4;
typedef __attribute__((ext_vector_type(8))) _Float16 h8;

static inline size_t align256(size_t x) { return (x + 255) & ~(size_t)255; }

// ---------------- w0 = dis * concat(ue, ie), fp16 ------------------------------
__global__ void k_concat_w(const float* __restrict__ ue, const float* __restrict__ ie,
                           const float* __restrict__ dis, h4* __restrict__ w) {
    int i = blockIdx.x * blockDim.x + threadIdx.x;   // h4 index (4 elems)
    const int totalU = N_USERS * 16;
    const int total  = N_NODES * 16;
    if (i >= total) return;
    float4 v = (i < totalU) ? ((const float4*)ue)[i] : ((const float4*)ie)[i - totalU];
    float s = dis[i >> 4];
    h4 o;
    o.x = (_Float16)(v.x * s); o.y = (_Float16)(v.y * s);
    o.z = (_Float16)(v.z * s); o.w = (_Float16)(v.w * s);
    w[i] = o;
}

// ---------------- count: per-block group histogram -> T[g*NBLK_A + b] ----------
__global__ void k_count(const int* __restrict__ src, int* __restrict__ T,
                        int nE, int epb) {
    __shared__ int h[NG];
    int tid = threadIdx.x, b = blockIdx.x;
    for (int i = tid; i < NG; i += 256) h[i] = 0;
    __syncthreads();
    int e0 = b * epb, e1 = min(e0 + epb, nE);
    for (int rb = e0; rb < e1; rb += 1024) {
        int e = rb + tid * 4;
        if (e + 3 < e1) {
            int4 s4 = *(const int4*)(src + e);
            atomicAdd(&h[s4.x >> GSH], 1);
            atomicAdd(&h[s4.y >> GSH], 1);
            atomicAdd(&h[s4.z >> GSH], 1);
            atomicAdd(&h[s4.w >> GSH], 1);
        } else {
            for (int j = 0; j < 4; ++j) {
                int ee = e + j;
                if (ee < e1) atomicAdd(&h[src[ee] >> GSH], 1);
            }
        }
    }
    __syncthreads();
    for (int i = tid; i < NG; i += 256) T[i * NBLK_A + b] = h[i];
}

// ---------------- 3-kernel exclusive scan of T (NT elems, in place) ------------
__global__ void k_scan1(int* __restrict__ T, int* __restrict__ btot) {
    __shared__ int ws[4];
    int blk = blockIdx.x, tid = threadIdx.x;
    int lane = tid & 63, wid = tid >> 6;
    int idx = blk * 1024 + tid * 4;
    int a0 = 0, a1 = 0, a2 = 0, a3 = 0;
    if (idx + 3 < NT) {
        int4 v = *(const int4*)(T + idx);
        a0 = v.x; a1 = v.y; a2 = v.z; a3 = v.w;
    } else {
        if (idx     < NT) a0 = T[idx];
        if (idx + 1 < NT) a1 = T[idx + 1];
        if (idx + 2 < NT) a2 = T[idx + 2];
        if (idx + 3 < NT) a3 = T[idx + 3];
    }
    int s = a0 + a1 + a2 + a3;
    int x = s;
#pragma unroll
    for (int off = 1; off < 64; off <<= 1) {
        int t = __shfl_up(x, off);
        if (lane >= off) x += t;
    }
    if (lane == 63) ws[wid] = x;
    __syncthreads();
    int woff = 0;
    for (int w = 0; w < wid; ++w) woff += ws[w];
    int excl = woff + x - s;
    if (idx + 3 < NT) {
        int4 o; o.x = excl; o.y = excl + a0; o.z = excl + a0 + a1; o.w = excl + a0 + a1 + a2;
        *(int4*)(T + idx) = o;
    } else {
        if (idx     < NT) T[idx]     = excl;
        if (idx + 1 < NT) T[idx + 1] = excl + a0;
        if (idx + 2 < NT) T[idx + 2] = excl + a0 + a1;
        if (idx + 3 < NT) T[idx + 3] = excl + a0 + a1 + a2;
    }
    if (tid == 255) btot[blk] = woff + x;
}

// 512 threads (8 waves): handles NSB2 = 293 entries
__global__ void k_scan2(int* __restrict__ btot) {
    __shared__ int ws[8];
    int tid = threadIdx.x, lane = tid & 63, wid = tid >> 6;
    int v = (tid < NSB2) ? btot[tid] : 0;
    int x = v;
#pragma unroll
    for (int off = 1; off < 64; off <<= 1) {
        int t = __shfl_up(x, off);
        if (lane >= off) x += t;
    }
    if (lane == 63) ws[wid] = x;
    __syncthreads();
    int woff = 0;
    for (int w = 0; w < wid; ++w) woff += ws[w];
    if (tid < NSB2) btot[tid] = woff + x - v;
}

__global__ void k_scan3(int* __restrict__ T, const int* __restrict__ btot) {
    int blk = blockIdx.x, tid = threadIdx.x;
    int idx = blk * 1024 + tid * 4;
    int add = btot[blk];
    if (idx + 3 < NT) {
        int4 v = *(int4*)(T + idx);
        v.x += add; v.y += add; v.z += add; v.w += add;
        *(int4*)(T + idx) = v;
    } else {
        if (idx     < NT) T[idx]     += add;
        if (idx + 1 < NT) T[idx + 1] += add;
        if (idx + 2 < NT) T[idx + 2] += add;
    }
}

// ---------------- scatter: block-local counting-sort placement -----------------
// rec = (src & 255) << 18 | dst
__global__ void k_scatterb(const int* __restrict__ src, const int* __restrict__ dst,
                           const int* __restrict__ T, unsigned int* __restrict__ brec,
                           int nE, int epb) {
    __shared__ int base_[NG];
    __shared__ int cur[NG];
    int tid = threadIdx.x, b = blockIdx.x;
    for (int i = tid; i < NG; i += 256) { base_[i] = T[i * NBLK_A + b]; cur[i] = 0; }
    __syncthreads();
    int e0 = b * epb, e1 = min(e0 + epb, nE);
    for (int rb = e0; rb < e1; rb += 1024) {
        int e = rb + tid * 4;
        if (e + 3 < e1) {
            int4 s4 = *(const int4*)(src + e);
            int4 d4 = *(const int4*)(dst + e);
#pragma unroll
            for (int j = 0; j < 4; ++j) {
                int s = (j == 0) ? s4.x : (j == 1) ? s4.y : (j == 2) ? s4.z : s4.w;
                int d = (j == 0) ? d4.x : (j == 1) ? d4.y : (j == 2) ? d4.z : d4.w;
                int g = s >> GSH;
                int c = atomicAdd(&cur[g], 1);
                brec[base_[g] + c] = ((unsigned int)(s & (GROUP - 1)) << 18) | (unsigned int)d;
            }
        } else {
            for (int j = 0; j < 4; ++j) {
                int ee = e + j;
                if (ee < e1) {
                    int s = src[ee];
                    int d = dst[ee];
                    int g = s >> GSH;
                    int c = atomicAdd(&cur[g], 1);
                    brec[base_[g] + c] = ((unsigned int)(s & (GROUP - 1)) << 18) | (unsigned int)d;
                }
            }
        }
    }
}

// ---------------- place: count + scan + tables + place (256-thread blocks) -----
__global__ void k_place(const int* __restrict__ T, const unsigned int* __restrict__ brec,
                        int* __restrict__ rowp, float* __restrict__ dis,
                        float* __restrict__ dis2, float* __restrict__ rdis,
                        int* __restrict__ cdst, int nE) {
    __shared__ int cnt[GROUP];   // counts, then reused as cursors
    __shared__ int ws[4];
    int g   = blockIdx.x;
    int nlo = g * GROUP;
    int gn  = min(GROUP, N_NODES - nlo);
    int tid = threadIdx.x;
    int lane = tid & 63, wid = tid >> 6;
    const int bs = GROUP;  // blockDim.x
    cnt[tid] = 0;
    __syncthreads();
    int beg  = T[g * NBLK_A];
    int endr = (g == NG - 1) ? nE : T[(g + 1) * NBLK_A];
    // count (x4 unrolled for MLP)
    {
        int i = beg + tid;
        for (; i + 3 * bs < endr; i += 4 * bs) {
            unsigned int r0 = brec[i], r1 = brec[i + bs];
            unsigned int r2 = brec[i + 2 * bs], r3 = brec[i + 3 * bs];
            atomicAdd(&cnt[r0 >> 18], 1);
            atomicAdd(&cnt[r1 >> 18], 1);
            atomicAdd(&cnt[r2 >> 18], 1);
            atomicAdd(&cnt[r3 >> 18], 1);
        }
        for (; i < endr; i += bs) atomicAdd(&cnt[brec[i] >> 18], 1);
    }
    __syncthreads();
    int mycnt = cnt[tid];
    // block-wide exclusive scan of 256 counts (4 waves)
    int x = mycnt;
#pragma unroll
    for (int off = 1; off < 64; off <<= 1) {
        int t = __shfl_up(x, off);
        if (lane >= off) x += t;
    }
    if (lane == 63) ws[wid] = x;
    __syncthreads();
    if (wid == 0 && lane < 4) {
        int s = ws[lane];
        int y = s;
#pragma unroll
        for (int off = 1; off < 4; off <<= 1) {
            int t = __shfl_up(y, off);
            if (lane >= off) y += t;
        }
        ws[lane] = y - s;   // exclusive
    }
    __syncthreads();
    int excl = ws[wid] + x - mycnt;
    if (tid < gn) {
        rowp[nlo + tid] = beg + excl;
        float c = (float)mycnt;
        dis [nlo + tid] = (mycnt > 0) ? 1.0f / sqrtf(c) : 0.0f;
        dis2[nlo + tid] = (mycnt > 0) ? 1.0f / c        : 0.0f;
        rdis[nlo + tid] = (mycnt > 0) ? sqrtf(c)        : 0.0f;
    }
    if (g == NG - 1 && tid == 0) rowp[N_NODES] = nE;
    cnt[tid] = beg + excl;   // cursors (tail -> group end: in-bounds)
    __syncthreads();
    // place (x4 unrolled)
    {
        int i = beg + tid;
        for (; i + 3 * bs < endr; i += 4 * bs) {
            unsigned int r0 = brec[i], r1 = brec[i + bs];
            unsigned int r2 = brec[i + 2 * bs], r3 = brec[i + 3 * bs];
            int p0 = atomicAdd(&cnt[r0 >> 18], 1);
            int p1 = atomicAdd(&cnt[r1 >> 18], 1);
            int p2 = atomicAdd(&cnt[r2 >> 18], 1);
            int p3 = atomicAdd(&cnt[r3 >> 18], 1);
            cdst[p0] = (int)(r0 & 0x3FFFFu);
            cdst[p1] = (int)(r1 & 0x3FFFFu);
            cdst[p2] = (int)(r2 & 0x3FFFFu);
            cdst[p3] = (int)(r3 & 0x3FFFFu);
        }
        for (; i < endr; i += bs) {
            unsigned int rec = brec[i];
            int pos = atomicAdd(&cnt[rec >> 18], 1);
            cdst[pos] = (int)(rec & 0x3FFFFu);
        }
    }
}

// ---------------- w-space SpMM: w_out[r] = dis2[r] * sum_{d in N(r)} w_in[d] ---
// nontemporal cdst loads + y8 store: keep L2 capacity for the x8 table
__global__ void k_spmm_w(const int* __restrict__ rowp, const int* __restrict__ cdst,
                         const float* __restrict__ dis2, const h8* __restrict__ x8,
                         h8* __restrict__ y8) {
    int gw   = (blockIdx.x * blockDim.x + threadIdx.x) >> 6;  // row (node)
    int lane = threadIdx.x & 63;
    if (gw >= N_NODES) return;
    int beg = rowp[gw], end = rowp[gw + 1];
    int g8 = lane >> 3;   // which of 8 concurrent edges
    int k  = lane & 7;    // h8 index within the 64-dim row (16B)
    float acc[8] = {0.f, 0.f, 0.f, 0.f, 0.f, 0.f, 0.f, 0.f};
    int len = end - beg;
    int n32 = len & ~31;
    int p = beg;
    for (; p < beg + n32; p += 32) {
        int e0 = p + g8, e1 = e0 + 8, e2 = e0 + 16, e3 = e0 + 24;
        int d0 = __builtin_nontemporal_load(cdst + e0);
        int d1 = __builtin_nontemporal_load(cdst + e1);
        int d2 = __builtin_nontemporal_load(cdst + e2);
        int d3 = __builtin_nontemporal_load(cdst + e3);
        h8 a = x8[(size_t)d0 * 8 + k];
        h8 b = x8[(size_t)d1 * 8 + k];
        h8 c = x8[(size_t)d2 * 8 + k];
        h8 d = x8[(size_t)d3 * 8 + k];
#pragma unroll
        for (int j = 0; j < 8; ++j)
            acc[j] += ((float)a[j] + (float)b[j]) + ((float)c[j] + (float)d[j]);
    }
    for (; p + g8 < end; p += 8) {
        int d = __builtin_nontemporal_load(cdst + p + g8);
        h8 a = x8[(size_t)d * 8 + k];
#pragma unroll
        for (int j = 0; j < 8; ++j)
            acc[j] += (float)a[j];
    }
#pragma unroll
    for (int off = 8; off < 64; off <<= 1) {
#pragma unroll
        for (int j = 0; j < 8; ++j)
            acc[j] += __shfl_xor(acc[j], off);
    }
    if (lane < 8) {
        float s = dis2[gw];
        h8 o;
#pragma unroll
        for (int j = 0; j < 8; ++j) o[j] = (_Float16)(acc[j] * s);
        __builtin_nontemporal_store(o, y8 + (size_t)gw * 8 + lane);
    }
}

// ---------------- acc = e0[q] + rdis*w1[q]  (init + layer-1 fused) -------------
__global__ void k_gather_w1(const int* __restrict__ users, const int* __restrict__ items,
                            const float* __restrict__ ue, const float* __restrict__ ie,
                            const float* __restrict__ rdis, const h4* __restrict__ w1,
                            float* __restrict__ acc) {
    int t = blockIdx.x * blockDim.x + threadIdx.x;
    int r = t >> 4;
    int k = t & 15;
    if (r >= 2 * NQ) return;
    int node = (r < NQ) ? users[r] : (N_USERS + items[r - NQ]);
    float4 v = (node < N_USERS)
        ? ((const float4*)ue)[(size_t)node * 16 + k]
        : ((const float4*)ie)[(size_t)(node - N_USERS) * 16 + k];
    h4 wv = w1[(size_t)node * 16 + k];
    float s = rdis[node];
    float4 c;
    c.x = v.x + s * (float)wv.x; c.y = v.y + s * (float)wv.y;
    c.z = v.z + s * (float)wv.z; c.w = v.w + s * (float)wv.w;
    ((float4*)acc)[(size_t)r * 16 + k] = c;
}

// ---------------- tail: layer-2 gather + layer-3 spmm + dot, one block/pair ----
__global__ void k_tail(const int* __restrict__ users, const int* __restrict__ items,
                       const int* __restrict__ rowp, const int* __restrict__ cdst,
                       const float* __restrict__ dis, const float* __restrict__ rdis,
                       const h8* __restrict__ x8, const float* __restrict__ acc,
                       float* __restrict__ out) {
    __shared__ float buf[2][64];
    int b = blockIdx.x;
    int w = threadIdx.x >> 6;      // 0: user row, 1: item row
    int lane = threadIdx.x & 63;
    int r = b + w * NQ;
    int node = (w == 0) ? users[b] : (N_USERS + items[b]);
    int beg = rowp[node], end = rowp[node + 1];
    int g8 = lane >> 3;
    int k  = lane & 7;
    float s[8] = {0.f, 0.f, 0.f, 0.f, 0.f, 0.f, 0.f, 0.f};
    int len = end - beg;
    int n32 = len & ~31;
    int p = beg;
    for (; p < beg + n32; p += 32) {
        int e0 = p + g8, e1 = e0 + 8, e2 = e0 + 16, e3 = e0 + 24;
        int d0 = __builtin_nontemporal_load(cdst + e0);
        int d1 = __builtin_nontemporal_load(cdst + e1);
        int d2 = __builtin_nontemporal_load(cdst + e2);
        int d3 = __builtin_nontemporal_load(cdst + e3);
        h8 a = x8[(size_t)d0 * 8 + k];
        h8 bb = x8[(size_t)d1 * 8 + k];
        h8 c = x8[(size_t)d2 * 8 + k];
        h8 d = x8[(size_t)d3 * 8 + k];
#pragma unroll
        for (int j = 0; j < 8; ++j)
            s[j] += ((float)a[j] + (float)bb[j]) + ((float)c[j] + (float)d[j]);
    }
    for (; p + g8 < end; p += 8) {
        int d = __builtin_nontemporal_load(cdst + p + g8);
        h8 a = x8[(size_t)d * 8 + k];
#pragma unroll
        for (int j = 0; j < 8; ++j)
            s[j] += (float)a[j];
    }
#pragma unroll
    for (int off = 8; off < 64; off <<= 1) {
#pragma unroll
        for (int j = 0; j < 8; ++j)
            s[j] += __shfl_xor(s[j], off);
    }
    if (lane < 8) {
        float dn = dis[node], rn = rdis[node];
        h8 wr = x8[(size_t)node * 8 + lane];
        const float* ap = acc + (size_t)r * DIM + lane * 8;
#pragma unroll
        for (int j = 0; j < 8; ++j)
            buf[w][lane * 8 + j] = ap[j] + rn * (float)wr[j] + dn * s[j];
    }
    __syncthreads();
    if (w == 0) {
        float pd = buf[0][lane] * buf[1][lane];
#pragma unroll
        for (int off = 1; off < 64; off <<= 1) pd += __shfl_xor(pd, off);
        if (lane == 0) out[b] = pd * (1.0f / 16.0f);
    }
}

// ---------------- fallback path (verified round 1), fp32 -----------------------
__global__ void k_spmm_atomic(const int* __restrict__ src, const int* __restrict__ dst,
                              const float* __restrict__ val, const float* __restrict__ x,
                              float* __restrict__ y, int nE) {
    int t = blockIdx.x * blockDim.x + threadIdx.x;
    int e = t >> 4;
    int k = t & 15;
    if (e >= nE) return;
    int   s = src[e];
    int   d = dst[e];
    float v = val[e];
    float4 xv = ((const float4*)x)[(size_t)d * 16 + k];
    float* yp = y + (size_t)s * DIM + k * 4;
    atomicAdd(yp + 0, v * xv.x);
    atomicAdd(yp + 1, v * xv.y);
    atomicAdd(yp + 2, v * xv.z);
    atomicAdd(yp + 3, v * xv.w);
}

__global__ void k_concat(const float* __restrict__ ue, const float* __restrict__ ie,
                         float* __restrict__ emb) {
    int i = blockIdx.x * blockDim.x + threadIdx.x;
    const int totalU = N_USERS * DIM / 4;
    const int total  = N_NODES * DIM / 4;
    if (i >= total) return;
    float4 v = (i < totalU) ? ((const float4*)ue)[i] : ((const float4*)ie)[i - totalU];
    ((float4*)emb)[i] = v;
}

__global__ void k_gather(const int* __restrict__ users, const int* __restrict__ items,
                         const float* __restrict__ emb, float* __restrict__ acc,
                         int init) {
    int t = blockIdx.x * blockDim.x + threadIdx.x;
    int r = t >> 4;
    int k = t & 15;
    if (r >= 2 * NQ) return;
    int node = (r < NQ) ? users[r] : (N_USERS + items[r - NQ]);
    float4 v = ((const float4*)emb)[(size_t)node * 16 + k];
    float4* a = ((float4*)acc) + (size_t)r * 16 + k;
    if (init) {
        *a = v;
    } else {
        float4 c = *a;
        c.x += v.x; c.y += v.y; c.z += v.z; c.w += v.w;
        *a = c;
    }
}

__global__ void k_dot(const float* __restrict__ acc, float* __restrict__ out) {
    int i = blockIdx.x * blockDim.x + threadIdx.x;
    if (i >= NQ) return;
    const float* u = acc + (size_t)i * DIM;
    const float* v = acc + (size_t)(NQ + i) * DIM;
    float s = 0.f;
#pragma unroll
    for (int d = 0; d < DIM; ++d) s += u[d] * v[d];
    out[i] = s * (1.0f / 16.0f);
}

extern "C" void kernel_launch(void* const* d_in, const int* in_sizes, int n_in,
                              void* d_out, int out_size, void* d_ws, size_t ws_size,
                              hipStream_t stream) {
    const float* ue    = (const float*)d_in[0];
    const float* ie    = (const float*)d_in[1];
    const int*   esrc  = (const int*)d_in[2];
    const int*   edst  = (const int*)d_in[3];
    const float* ev    = (const float*)d_in[4];
    const int*   users = (const int*)d_in[5];
    const int*   items = (const int*)d_in[6];
    float* out = (float*)d_out;
    const int nE = in_sizes[2];

    const size_t embHB = (size_t)N_NODES * DIM * sizeof(_Float16); // 19.2 MB
    const size_t accB  = (size_t)2 * NQ * DIM * sizeof(float);     // 2 MB
    const size_t rpB   = (size_t)(N_NODES + 1) * sizeof(int);
    const size_t disB  = (size_t)N_NODES * sizeof(float);
    const size_t tB    = (size_t)NT * sizeof(int);
    const size_t btB   = (size_t)NSB2 * sizeof(int);
    const size_t cdB   = (size_t)nE * sizeof(int);

    size_t o = 0;
    char* base = (char*)d_ws;
    h4*    w0    = (h4*)   (base + o); o = align256(o + embHB);
    h4*    w1    = (h4*)   (base + o); o = align256(o + embHB);
    float* acc   = (float*)(base + o); o = align256(o + accB);
    int*   rowp  = (int*)  (base + o); o = align256(o + rpB);
    float* dis   = (float*)(base + o); o = align256(o + disB);
    float* dis2  = (float*)(base + o); o = align256(o + disB);
    float* rdis  = (float*)(base + o); o = align256(o + disB);
    int*   T     = (int*)  (base + o); o = align256(o + tB);
    int*   btot  = (int*)  (base + o); o = align256(o + btB);
    int*   cdst  = (int*)  (base + o); o = align256(o + cdB);
    unsigned int* brec = (unsigned int*)(base + o); o = align256(o + cdB);
    const bool csr_ok = (o <= ws_size);

    if (csr_ok) {
        int epb = ((nE + NBLK_A - 1) / NBLK_A + 3) & ~3;   // multiple of 4

        // ---- build CSR ----
        k_count<<<NBLK_A, 256, 0, stream>>>(esrc, T, nE, epb);
        k_scan1<<<NSB2, 256, 0, stream>>>(T, btot);
        k_scan2<<<1, 512, 0, stream>>>(btot);
        k_scan3<<<NSB2, 256, 0, stream>>>(T, btot);
        k_scatterb<<<NBLK_A, 256, 0, stream>>>(esrc, edst, T, brec, nE, epb);
        k_place<<<NG, GROUP, 0, stream>>>(T, brec, rowp, dis, dis2, rdis, cdst, nE);

        // ---- w0, layer 1 full (+fused acc init), layer 2 full, fused tail ----
        const int totalH4 = N_NODES * 16;
        k_concat_w<<<(totalH4 + 255) / 256, 256, 0, stream>>>(ue, ie, dis, w0);
        const int spmmBlocks = (N_NODES * 64 + 255) / 256;
        k_spmm_w<<<spmmBlocks, 256, 0, stream>>>(rowp, cdst, dis2, (const h8*)w0, (h8*)w1);
        k_gather_w1<<<(2 * NQ * 16 + 255) / 256, 256, 0, stream>>>(users, items, ue, ie,
                                                                   rdis, w1, acc);
        k_spmm_w<<<spmmBlocks, 256, 0, stream>>>(rowp, cdst, dis2, (const h8*)w1, (h8*)w0);
        k_tail<<<NQ, 128, 0, stream>>>(users, items, rowp, cdst, dis, rdis,
                                       (const h8*)w0, acc, out);
    } else {
        // ---- fallback: atomic scatter path (verified round 1), fp32 ----
        const size_t embB = (size_t)N_NODES * DIM * sizeof(float);
        size_t o2 = 0;
        float* emb0 = (float*)(base + o2); o2 = align256(o2 + embB);
        float* emb1 = (float*)(base + o2); o2 = align256(o2 + embB);
        float* acc2 = (float*)(base + o2); o2 = align256(o2 + accB);
        const int totalV4 = N_NODES * DIM / 4;
        k_concat<<<(totalV4 + 255) / 256, 256, 0, stream>>>(ue, ie, emb0);
        k_gather<<<(2 * NQ * 16 + 255) / 256, 256, 0, stream>>>(users, items, emb0, acc2, 1);
        float* cur = emb0;
        float* nxt = emb1;
        for (int l = 0; l < 3; ++l) {
            hipMemsetAsync(nxt, 0, embB, stream);
            long threads = (long)nE * 16;
            k_spmm_atomic<<<(int)((threads + 255) / 256), 256, 0, stream>>>(esrc, edst, ev, cur, nxt, nE);
            k_gather<<<(2 * NQ * 16 + 255) / 256, 256, 0, stream>>>(users, items, nxt, acc2, 0);
            float* tmp = cur; cur = nxt; nxt = tmp;
        }
        k_dot<<<(NQ + 255) / 256, 256, 0, stream>>>(acc2, out);
    }
}

// Round 14
// 310.644 us; speedup vs baseline: 1.0777x; 1.0777x over previous
//
#include <hip/hip_runtime.h>

#define N_USERS 100000
#define N_ITEMS 50000
#define N_NODES 150000   // N_USERS + N_ITEMS
#define DIM 64
#define NQ 4096
#define GROUP 256
#define GSH 8
#define NG ((N_NODES + GROUP - 1) / GROUP)   // 586 groups of 256 nodes
#define NBLK_A 512
#define NT (NG * NBLK_A)                      // 300032 count-table entries
#define NSB2 ((NT + 1023) / 1024)             // 293 scan chunks

typedef __attribute__((ext_vector_type(4))) _Float16 h4;
typedef __attribute__((ext_vector_type(8))) _Float16 h8;

static inline size_t align256(size_t x) { return (x + 255) & ~(size_t)255; }

// ---------------- w0 = dis * concat(ue, ie), fp16 ------------------------------
__global__ void k_concat_w(const float* __restrict__ ue, const float* __restrict__ ie,
                           const float* __restrict__ dis, h4* __restrict__ w) {
    int i = blockIdx.x * blockDim.x + threadIdx.x;   // h4 index (4 elems)
    const int totalU = N_USERS * 16;
    const int total  = N_NODES * 16;
    if (i >= total) return;
    float4 v = (i < totalU) ? ((const float4*)ue)[i] : ((const float4*)ie)[i - totalU];
    float s = dis[i >> 4];
    h4 o;
    o.x = (_Float16)(v.x * s); o.y = (_Float16)(v.y * s);
    o.z = (_Float16)(v.z * s); o.w = (_Float16)(v.w * s);
    w[i] = o;
}

// ---------------- count: per-block group histogram -> T[g*NBLK_A + b] ----------
__global__ void k_count(const int* __restrict__ src, int* __restrict__ T,
                        int nE, int epb) {
    __shared__ int h[NG];
    int tid = threadIdx.x, b = blockIdx.x;
    for (int i = tid; i < NG; i += 256) h[i] = 0;
    __syncthreads();
    int e0 = b * epb, e1 = min(e0 + epb, nE);
    for (int rb = e0; rb < e1; rb += 1024) {
        int e = rb + tid * 4;
        if (e + 3 < e1) {
            int4 s4 = *(const int4*)(src + e);
            atomicAdd(&h[s4.x >> GSH], 1);
            atomicAdd(&h[s4.y >> GSH], 1);
            atomicAdd(&h[s4.z >> GSH], 1);
            atomicAdd(&h[s4.w >> GSH], 1);
        } else {
            for (int j = 0; j < 4; ++j) {
                int ee = e + j;
                if (ee < e1) atomicAdd(&h[src[ee] >> GSH], 1);
            }
        }
    }
    __syncthreads();
    for (int i = tid; i < NG; i += 256) T[i * NBLK_A + b] = h[i];
}

// ---------------- 3-kernel exclusive scan of T (NT elems, in place) ------------
__global__ void k_scan1(int* __restrict__ T, int* __restrict__ btot) {
    __shared__ int ws[4];
    int blk = blockIdx.x, tid = threadIdx.x;
    int lane = tid & 63, wid = tid >> 6;
    int idx = blk * 1024 + tid * 4;
    int a0 = 0, a1 = 0, a2 = 0, a3 = 0;
    if (idx + 3 < NT) {
        int4 v = *(const int4*)(T + idx);
        a0 = v.x; a1 = v.y; a2 = v.z; a3 = v.w;
    } else {
        if (idx     < NT) a0 = T[idx];
        if (idx + 1 < NT) a1 = T[idx + 1];
        if (idx + 2 < NT) a2 = T[idx + 2];
        if (idx + 3 < NT) a3 = T[idx + 3];
    }
    int s = a0 + a1 + a2 + a3;
    int x = s;
#pragma unroll
    for (int off = 1; off < 64; off <<= 1) {
        int t = __shfl_up(x, off);
        if (lane >= off) x += t;
    }
    if (lane == 63) ws[wid] = x;
    __syncthreads();
    int woff = 0;
    for (int w = 0; w < wid; ++w) woff += ws[w];
    int excl = woff + x - s;
    if (idx + 3 < NT) {
        int4 o; o.x = excl; o.y = excl + a0; o.z = excl + a0 + a1; o.w = excl + a0 + a1 + a2;
        *(int4*)(T + idx) = o;
    } else {
        if (idx     < NT) T[idx]     = excl;
        if (idx + 1 < NT) T[idx + 1] = excl + a0;
        if (idx + 2 < NT) T[idx + 2] = excl + a0 + a1;
        if (idx + 3 < NT) T[idx + 3] = excl + a0 + a1 + a2;
    }
    if (tid == 255) btot[blk] = woff + x;
}

// 512 threads (8 waves): handles NSB2 = 293 entries
__global__ void k_scan2(int* __restrict__ btot) {
    __shared__ int ws[8];
    int tid = threadIdx.x, lane = tid & 63, wid = tid >> 6;
    int v = (tid < NSB2) ? btot[tid] : 0;
    int x = v;
#pragma unroll
    for (int off = 1; off < 64; off <<= 1) {
        int t = __shfl_up(x, off);
        if (lane >= off) x += t;
    }
    if (lane == 63) ws[wid] = x;
    __syncthreads();
    int woff = 0;
    for (int w = 0; w < wid; ++w) woff += ws[w];
    if (tid < NSB2) btot[tid] = woff + x - v;
}

__global__ void k_scan3(int* __restrict__ T, const int* __restrict__ btot) {
    int blk = blockIdx.x, tid = threadIdx.x;
    int idx = blk * 1024 + tid * 4;
    int add = btot[blk];
    if (idx + 3 < NT) {
        int4 v = *(int4*)(T + idx);
        v.x += add; v.y += add; v.z += add; v.w += add;
        *(int4*)(T + idx) = v;
    } else {
        if (idx     < NT) T[idx]     += add;
        if (idx + 1 < NT) T[idx + 1] += add;
        if (idx + 2 < NT) T[idx + 2] += add;
    }
}

// ---------------- scatter: block-local counting-sort placement -----------------
// rec = (src & 255) << 18 | dst
__global__ void k_scatterb(const int* __restrict__ src, const int* __restrict__ dst,
                           const int* __restrict__ T, unsigned int* __restrict__ brec,
                           int nE, int epb) {
    __shared__ int base_[NG];
    __shared__ int cur[NG];
    int tid = threadIdx.x, b = blockIdx.x;
    for (int i = tid; i < NG; i += 256) { base_[i] = T[i * NBLK_A + b]; cur[i] = 0; }
    __syncthreads();
    int e0 = b * epb, e1 = min(e0 + epb, nE);
    for (int rb = e0; rb < e1; rb += 1024) {
        int e = rb + tid * 4;
        if (e + 3 < e1) {
            int4 s4 = *(const int4*)(src + e);
            int4 d4 = *(const int4*)(dst + e);
#pragma unroll
            for (int j = 0; j < 4; ++j) {
                int s = (j == 0) ? s4.x : (j == 1) ? s4.y : (j == 2) ? s4.z : s4.w;
                int d = (j == 0) ? d4.x : (j == 1) ? d4.y : (j == 2) ? d4.z : d4.w;
                int g = s >> GSH;
                int c = atomicAdd(&cur[g], 1);
                brec[base_[g] + c] = ((unsigned int)(s & (GROUP - 1)) << 18) | (unsigned int)d;
            }
        } else {
            for (int j = 0; j < 4; ++j) {
                int ee = e + j;
                if (ee < e1) {
                    int s = src[ee];
                    int d = dst[ee];
                    int g = s >> GSH;
                    int c = atomicAdd(&cur[g], 1);
                    brec[base_[g] + c] = ((unsigned int)(s & (GROUP - 1)) << 18) | (unsigned int)d;
                }
            }
        }
    }
}

// ---------------- place: count + scan + tables + place (256-thread blocks) -----
__global__ void k_place(const int* __restrict__ T, const unsigned int* __restrict__ brec,
                        int* __restrict__ rowp, float* __restrict__ dis,
                        float* __restrict__ dis2, float* __restrict__ rdis,
                        int* __restrict__ cdst, int nE) {
    __shared__ int cnt[GROUP];   // counts, then reused as cursors
    __shared__ int ws[4];
    int g   = blockIdx.x;
    int nlo = g * GROUP;
    int gn  = min(GROUP, N_NODES - nlo);
    int tid = threadIdx.x;
    int lane = tid & 63, wid = tid >> 6;
    const int bs = GROUP;  // blockDim.x
    cnt[tid] = 0;
    __syncthreads();
    int beg  = T[g * NBLK_A];
    int endr = (g == NG - 1) ? nE : T[(g + 1) * NBLK_A];
    // count (x4 unrolled for MLP)
    {
        int i = beg + tid;
        for (; i + 3 * bs < endr; i += 4 * bs) {
            unsigned int r0 = brec[i], r1 = brec[i + bs];
            unsigned int r2 = brec[i + 2 * bs], r3 = brec[i + 3 * bs];
            atomicAdd(&cnt[r0 >> 18], 1);
            atomicAdd(&cnt[r1 >> 18], 1);
            atomicAdd(&cnt[r2 >> 18], 1);
            atomicAdd(&cnt[r3 >> 18], 1);
        }
        for (; i < endr; i += bs) atomicAdd(&cnt[brec[i] >> 18], 1);
    }
    __syncthreads();
    int mycnt = cnt[tid];
    // block-wide exclusive scan of 256 counts (4 waves)
    int x = mycnt;
#pragma unroll
    for (int off = 1; off < 64; off <<= 1) {
        int t = __shfl_up(x, off);
        if (lane >= off) x += t;
    }
    if (lane == 63) ws[wid] = x;
    __syncthreads();
    if (wid == 0 && lane < 4) {
        int s = ws[lane];
        int y = s;
#pragma unroll
        for (int off = 1; off < 4; off <<= 1) {
            int t = __shfl_up(y, off);
            if (lane >= off) y += t;
        }
        ws[lane] = y - s;   // exclusive
    }
    __syncthreads();
    int excl = ws[wid] + x - mycnt;
    if (tid < gn) {
        rowp[nlo + tid] = beg + excl;
        float c = (float)mycnt;
        dis [nlo + tid] = (mycnt > 0) ? 1.0f / sqrtf(c) : 0.0f;
        dis2[nlo + tid] = (mycnt > 0) ? 1.0f / c        : 0.0f;
        rdis[nlo + tid] = (mycnt > 0) ? sqrtf(c)        : 0.0f;
    }
    if (g == NG - 1 && tid == 0) rowp[N_NODES] = nE;
    cnt[tid] = beg + excl;   // cursors (tail -> group end: in-bounds)
    __syncthreads();
    // place (x4 unrolled)
    {
        int i = beg + tid;
        for (; i + 3 * bs < endr; i += 4 * bs) {
            unsigned int r0 = brec[i], r1 = brec[i + bs];
            unsigned int r2 = brec[i + 2 * bs], r3 = brec[i + 3 * bs];
            int p0 = atomicAdd(&cnt[r0 >> 18], 1);
            int p1 = atomicAdd(&cnt[r1 >> 18], 1);
            int p2 = atomicAdd(&cnt[r2 >> 18], 1);
            int p3 = atomicAdd(&cnt[r3 >> 18], 1);
            cdst[p0] = (int)(r0 & 0x3FFFFu);
            cdst[p1] = (int)(r1 & 0x3FFFFu);
            cdst[p2] = (int)(r2 & 0x3FFFFu);
            cdst[p3] = (int)(r3 & 0x3FFFFu);
        }
        for (; i < endr; i += bs) {
            unsigned int rec = brec[i];
            int pos = atomicAdd(&cnt[rec >> 18], 1);
            cdst[pos] = (int)(rec & 0x3FFFFu);
        }
    }
}

// ---------------- w-space SpMM: w_out[r] = dis2[r] * sum_{d in N(r)} w_in[d] ---
__global__ void k_spmm_w(const int* __restrict__ rowp, const int* __restrict__ cdst,
                         const float* __restrict__ dis2, const h8* __restrict__ x8,
                         h8* __restrict__ y8) {
    int gw   = (blockIdx.x * blockDim.x + threadIdx.x) >> 6;  // row (node)
    int lane = threadIdx.x & 63;
    if (gw >= N_NODES) return;
    int beg = rowp[gw], end = rowp[gw + 1];
    int g8 = lane >> 3;   // which of 8 concurrent edges
    int k  = lane & 7;    // h8 index within the 64-dim row (16B)
    float acc[8] = {0.f, 0.f, 0.f, 0.f, 0.f, 0.f, 0.f, 0.f};
    int len = end - beg;
    int n32 = len & ~31;
    int p = beg;
    for (; p < beg + n32; p += 32) {
        int e0 = p + g8, e1 = e0 + 8, e2 = e0 + 16, e3 = e0 + 24;
        int d0 = cdst[e0], d1 = cdst[e1], d2 = cdst[e2], d3 = cdst[e3];
        h8 a = x8[(size_t)d0 * 8 + k];
        h8 b = x8[(size_t)d1 * 8 + k];
        h8 c = x8[(size_t)d2 * 8 + k];
        h8 d = x8[(size_t)d3 * 8 + k];
#pragma unroll
        for (int j = 0; j < 8; ++j)
            acc[j] += ((float)a[j] + (float)b[j]) + ((float)c[j] + (float)d[j]);
    }
    for (; p + g8 < end; p += 8) {
        int d = cdst[p + g8];
        h8 a = x8[(size_t)d * 8 + k];
#pragma unroll
        for (int j = 0; j < 8; ++j)
            acc[j] += (float)a[j];
    }
#pragma unroll
    for (int off = 8; off < 64; off <<= 1) {
#pragma unroll
        for (int j = 0; j < 8; ++j)
            acc[j] += __shfl_xor(acc[j], off);
    }
    if (lane < 8) {
        float s = dis2[gw];
        h8 o;
#pragma unroll
        for (int j = 0; j < 8; ++j) o[j] = (_Float16)(acc[j] * s);
        y8[(size_t)gw * 8 + lane] = o;
    }
}

// ---------------- acc = e0[q] + rdis*w1[q]  (init + layer-1 fused) -------------
__global__ void k_gather_w1(const int* __restrict__ users, const int* __restrict__ items,
                            const float* __restrict__ ue, const float* __restrict__ ie,
                            const float* __restrict__ rdis, const h4* __restrict__ w1,
                            float* __restrict__ acc) {
    int t = blockIdx.x * blockDim.x + threadIdx.x;
    int r = t >> 4;
    int k = t & 15;
    if (r >= 2 * NQ) return;
    int node = (r < NQ) ? users[r] : (N_USERS + items[r - NQ]);
    float4 v = (node < N_USERS)
        ? ((const float4*)ue)[(size_t)node * 16 + k]
        : ((const float4*)ie)[(size_t)(node - N_USERS) * 16 + k];
    h4 wv = w1[(size_t)node * 16 + k];
    float s = rdis[node];
    float4 c;
    c.x = v.x + s * (float)wv.x; c.y = v.y + s * (float)wv.y;
    c.z = v.z + s * (float)wv.z; c.w = v.w + s * (float)wv.w;
    ((float4*)acc)[(size_t)r * 16 + k] = c;
}

// ---------------- tail: layer-2 gather + layer-3 spmm + dot, one block/pair ----
__global__ void k_tail(const int* __restrict__ users, const int* __restrict__ items,
                       const int* __restrict__ rowp, const int* __restrict__ cdst,
                       const float* __restrict__ dis, const float* __restrict__ rdis,
                       const h8* __restrict__ x8, const float* __restrict__ acc,
                       float* __restrict__ out) {
    __shared__ float buf[2][64];
    int b = blockIdx.x;
    int w = threadIdx.x >> 6;      // 0: user row, 1: item row
    int lane = threadIdx.x & 63;
    int r = b + w * NQ;
    int node = (w == 0) ? users[b] : (N_USERS + items[b]);
    int beg = rowp[node], end = rowp[node + 1];
    int g8 = lane >> 3;
    int k  = lane & 7;
    float s[8] = {0.f, 0.f, 0.f, 0.f, 0.f, 0.f, 0.f, 0.f};
    int len = end - beg;
    int n32 = len & ~31;
    int p = beg;
    for (; p < beg + n32; p += 32) {
        int e0 = p + g8, e1 = e0 + 8, e2 = e0 + 16, e3 = e0 + 24;
        int d0 = cdst[e0], d1 = cdst[e1], d2 = cdst[e2], d3 = cdst[e3];
        h8 a = x8[(size_t)d0 * 8 + k];
        h8 bb = x8[(size_t)d1 * 8 + k];
        h8 c = x8[(size_t)d2 * 8 + k];
        h8 d = x8[(size_t)d3 * 8 + k];
#pragma unroll
        for (int j = 0; j < 8; ++j)
            s[j] += ((float)a[j] + (float)bb[j]) + ((float)c[j] + (float)d[j]);
    }
    for (; p + g8 < end; p += 8) {
        int d = cdst[p + g8];
        h8 a = x8[(size_t)d * 8 + k];
#pragma unroll
        for (int j = 0; j < 8; ++j)
            s[j] += (float)a[j];
    }
#pragma unroll
    for (int off = 8; off < 64; off <<= 1) {
#pragma unroll
        for (int j = 0; j < 8; ++j)
            s[j] += __shfl_xor(s[j], off);
    }
    if (lane < 8) {
        float dn = dis[node], rn = rdis[node];
        h8 wr = x8[(size_t)node * 8 + lane];
        const float* ap = acc + (size_t)r * DIM + lane * 8;
#pragma unroll
        for (int j = 0; j < 8; ++j)
            buf[w][lane * 8 + j] = ap[j] + rn * (float)wr[j] + dn * s[j];
    }
    __syncthreads();
    if (w == 0) {
        float pd = buf[0][lane] * buf[1][lane];
#pragma unroll
        for (int off = 1; off < 64; off <<= 1) pd += __shfl_xor(pd, off);
        if (lane == 0) out[b] = pd * (1.0f / 16.0f);
    }
}

// ---------------- fallback path (verified round 1), fp32 -----------------------
__global__ void k_spmm_atomic(const int* __restrict__ src, const int* __restrict__ dst,
                              const float* __restrict__ val, const float* __restrict__ x,
                              float* __restrict__ y, int nE) {
    int t = blockIdx.x * blockDim.x + threadIdx.x;
    int e = t >> 4;
    int k = t & 15;
    if (e >= nE) return;
    int   s = src[e];
    int   d = dst[e];
    float v = val[e];
    float4 xv = ((const float4*)x)[(size_t)d * 16 + k];
    float* yp = y + (size_t)s * DIM + k * 4;
    atomicAdd(yp + 0, v * xv.x);
    atomicAdd(yp + 1, v * xv.y);
    atomicAdd(yp + 2, v * xv.z);
    atomicAdd(yp + 3, v * xv.w);
}

__global__ void k_concat(const float* __restrict__ ue, const float* __restrict__ ie,
                         float* __restrict__ emb) {
    int i = blockIdx.x * blockDim.x + threadIdx.x;
    const int totalU = N_USERS * DIM / 4;
    const int total  = N_NODES * DIM / 4;
    if (i >= total) return;
    float4 v = (i < totalU) ? ((const float4*)ue)[i] : ((const float4*)ie)[i - totalU];
    ((float4*)emb)[i] = v;
}

__global__ void k_gather(const int* __restrict__ users, const int* __restrict__ items,
                         const float* __restrict__ emb, float* __restrict__ acc,
                         int init) {
    int t = blockIdx.x * blockDim.x + threadIdx.x;
    int r = t >> 4;
    int k = t & 15;
    if (r >= 2 * NQ) return;
    int node = (r < NQ) ? users[r] : (N_USERS + items[r - NQ]);
    float4 v = ((const float4*)emb)[(size_t)node * 16 + k];
    float4* a = ((float4*)acc) + (size_t)r * 16 + k;
    if (init) {
        *a = v;
    } else {
        float4 c = *a;
        c.x += v.x; c.y += v.y; c.z += v.z; c.w += v.w;
        *a = c;
    }
}

__global__ void k_dot(const float* __restrict__ acc, float* __restrict__ out) {
    int i = blockIdx.x * blockDim.x + threadIdx.x;
    if (i >= NQ) return;
    const float* u = acc + (size_t)i * DIM;
    const float* v = acc + (size_t)(NQ + i) * DIM;
    float s = 0.f;
#pragma unroll
    for (int d = 0; d < DIM; ++d) s += u[d] * v[d];
    out[i] = s * (1.0f / 16.0f);
}

extern "C" void kernel_launch(void* const* d_in, const int* in_sizes, int n_in,
                              void* d_out, int out_size, void* d_ws, size_t ws_size,
                              hipStream_t stream) {
    const float* ue    = (const float*)d_in[0];
    const float* ie    = (const float*)d_in[1];
    const int*   esrc  = (const int*)d_in[2];
    const int*   edst  = (const int*)d_in[3];
    const float* ev    = (const float*)d_in[4];
    const int*   users = (const int*)d_in[5];
    const int*   items = (const int*)d_in[6];
    float* out = (float*)d_out;
    const int nE = in_sizes[2];

    const size_t embHB = (size_t)N_NODES * DIM * sizeof(_Float16); // 19.2 MB
    const size_t accB  = (size_t)2 * NQ * DIM * sizeof(float);     // 2 MB
    const size_t rpB   = (size_t)(N_NODES + 1) * sizeof(int);
    const size_t disB  = (size_t)N_NODES * sizeof(float);
    const size_t tB    = (size_t)NT * sizeof(int);
    const size_t btB   = (size_t)NSB2 * sizeof(int);
    const size_t cdB   = (size_t)nE * sizeof(int);

    size_t o = 0;
    char* base = (char*)d_ws;
    h4*    w0    = (h4*)   (base + o); o = align256(o + embHB);
    h4*    w1    = (h4*)   (base + o); o = align256(o + embHB);
    float* acc   = (float*)(base + o); o = align256(o + accB);
    int*   rowp  = (int*)  (base + o); o = align256(o + rpB);
    float* dis   = (float*)(base + o); o = align256(o + disB);
    float* dis2  = (float*)(base + o); o = align256(o + disB);
    float* rdis  = (float*)(base + o); o = align256(o + disB);
    int*   T     = (int*)  (base + o); o = align256(o + tB);
    int*   btot  = (int*)  (base + o); o = align256(o + btB);
    int*   cdst  = (int*)  (base + o); o = align256(o + cdB);
    unsigned int* brec = (unsigned int*)(base + o); o = align256(o + cdB);
    const bool csr_ok = (o <= ws_size);

    if (csr_ok) {
        int epb = ((nE + NBLK_A - 1) / NBLK_A + 3) & ~3;   // multiple of 4

        // ---- build CSR ----
        k_count<<<NBLK_A, 256, 0, stream>>>(esrc, T, nE, epb);
        k_scan1<<<NSB2, 256, 0, stream>>>(T, btot);
        k_scan2<<<1, 512, 0, stream>>>(btot);
        k_scan3<<<NSB2, 256, 0, stream>>>(T, btot);
        k_scatterb<<<NBLK_A, 256, 0, stream>>>(esrc, edst, T, brec, nE, epb);
        k_place<<<NG, GROUP, 0, stream>>>(T, brec, rowp, dis, dis2, rdis, cdst, nE);

        // ---- w0, layer 1 full (+fused acc init), layer 2 full, fused tail ----
        const int totalH4 = N_NODES * 16;
        k_concat_w<<<(totalH4 + 255) / 256, 256, 0, stream>>>(ue, ie, dis, w0);
        const int spmmBlocks = (N_NODES * 64 + 255) / 256;
        k_spmm_w<<<spmmBlocks, 256, 0, stream>>>(rowp, cdst, dis2, (const h8*)w0, (h8*)w1);
        k_gather_w1<<<(2 * NQ * 16 + 255) / 256, 256, 0, stream>>>(users, items, ue, ie,
                                                                   rdis, w1, acc);
        k_spmm_w<<<spmmBlocks, 256, 0, stream>>>(rowp, cdst, dis2, (const h8*)w1, (h8*)w0);
        k_tail<<<NQ, 128, 0, stream>>>(users, items, rowp, cdst, dis, rdis,
                                       (const h8*)w0, acc, out);
    } else {
        // ---- fallback: atomic scatter path (verified round 1), fp32 ----
        const size_t embB = (size_t)N_NODES * DIM * sizeof(float);
        size_t o2 = 0;
        float* emb0 = (float*)(base + o2); o2 = align256(o2 + embB);
        float* emb1 = (float*)(base + o2); o2 = align256(o2 + embB);
        float* acc2 = (float*)(base + o2); o2 = align256(o2 + accB);
        const int totalV4 = N_NODES * DIM / 4;
        k_concat<<<(totalV4 + 255) / 256, 256, 0, stream>>>(ue, ie, emb0);
        k_gather<<<(2 * NQ * 16 + 255) / 256, 256, 0, stream>>>(users, items, emb0, acc2, 1);
        float* cur = emb0;
        float* nxt = emb1;
        for (int l = 0; l < 3; ++l) {
            hipMemsetAsync(nxt, 0, embB, stream);
            long threads = (long)nE * 16;
            k_spmm_atomic<<<(int)((threads + 255) / 256), 256, 0, stream>>>(esrc, edst, ev, cur, nxt, nE);
            k_gather<<<(2 * NQ * 16 + 255) / 256, 256, 0, stream>>>(users, items, nxt, acc2, 0);
            float* tmp = cur; cur = nxt; nxt = tmp;
        }
        k_dot<<<(NQ + 255) / 256, 256, 0, stream>>>(acc2, out);
    }
}